// Round 2
// 76.858 us; speedup vs baseline: 1.1000x; 1.1000x over previous
//
#include <hip/hip_runtime.h>
#include <stdint.h>

#define O_DIM 512
#define D_DIM 128
#define LR 0.01f
// 1 / (2 * sigma^2), sigma = 256 -> 1/131072
#define INV2SIG2 7.62939453125e-6f

typedef float f32x4 __attribute__((ext_vector_type(4)));

// ---------------- fast path ----------------
// ws layout:
//   [0, 1 MiB)          : dist[512][512]      float
//   [1 MiB, 2 MiB)      : Spart[4][512][128]  float
//   [2 MiB, 2.25 MiB)   : S[512][128]         float (reduced in som_argmin)

// Pass 1: block = (j, b-chunk of 128). 4 waves; each wave handles 4 b's at a
// time with 16 lanes per b (8 d-elements per lane) -> distance reduce is
// 8 in-register FMAs + 4 shfl_xor steps per 4 b's (1 DS op per (b,j) instead
// of 6), keeping the kernel on the 134 MB HBM-read floor.
__global__ __launch_bounds__(256) void som_pass1(
    const float* __restrict__ X,
    const float* __restrict__ W,
    float* __restrict__ dist,
    float* __restrict__ Spart)
{
    const int j     = blockIdx.x >> 2;   // 0..511
    const int chunk = blockIdx.x & 3;    // 0..3
    const int wave  = threadIdx.x >> 6;  // 0..3
    const int lane  = threadIdx.x & 63;
    const int g     = lane >> 4;         // b-subgroup 0..3
    const int i16   = lane & 15;         // d-range within row
    const int dA    = i16 * 4;           // floats [dA, dA+4)
    const int dB    = 64 + dA;           // floats [dB, dB+4)

    float acc[8];
    #pragma unroll
    for (int u = 0; u < 8; ++u) acc[u] = 0.f;

    const int bbase = chunk * 128 + wave * 32 + g;   // + k*4, k=0..7

    #pragma unroll 2
    for (int k = 0; k < 8; ++k) {
        const int b = bbase + k * 4;
        const float* wrow = W + ((size_t)b * O_DIM + j) * D_DIM;
        const float* xrow = X + (size_t)b * D_DIM;
        const float4 wa = *(const float4*)(wrow + dA);
        const float4 wb = *(const float4*)(wrow + dB);
        const float4 xa = *(const float4*)(xrow + dA);
        const float4 xb = *(const float4*)(xrow + dB);

        float dx[8];
        dx[0] = wa.x - xa.x; dx[1] = wa.y - xa.y;
        dx[2] = wa.z - xa.z; dx[3] = wa.w - xa.w;
        dx[4] = wb.x - xb.x; dx[5] = wb.y - xb.y;
        dx[6] = wb.z - xb.z; dx[7] = wb.w - xb.w;

        float s = 0.f;
        #pragma unroll
        for (int u = 0; u < 8; ++u) s = fmaf(dx[u], dx[u], s);
        // reduce across the 16 lanes of this b
        s += __shfl_xor(s, 1, 64);
        s += __shfl_xor(s, 2, 64);
        s += __shfl_xor(s, 4, 64);
        s += __shfl_xor(s, 8, 64);

        if (i16 == 0) dist[(size_t)b * O_DIM + j] = s;

        const float c = LR * __expf(-s * INV2SIG2);
        #pragma unroll
        for (int u = 0; u < 8; ++u) acc[u] = fmaf(-c, dx[u], acc[u]); // c*(x-w)
    }

    // sum the 4 b-subgroups (lanes i16, i16+16, i16+32, i16+48)
    #pragma unroll
    for (int u = 0; u < 8; ++u) {
        acc[u] += __shfl_xor(acc[u], 16, 64);
        acc[u] += __shfl_xor(acc[u], 32, 64);
    }

    __shared__ float sacc[4][D_DIM];
    if (g == 0) {
        #pragma unroll
        for (int u = 0; u < 4; ++u) {
            sacc[wave][dA + u] = acc[u];
            sacc[wave][dB + u] = acc[4 + u];
        }
    }
    __syncthreads();
    if (threadIdx.x < D_DIM) {
        const int d = threadIdx.x;
        Spart[((size_t)chunk * O_DIM + j) * D_DIM + d] =
            sacc[0][d] + sacc[1][d] + sacc[2][d] + sacc[3][d];
    }
}

// argmin over j per row b + fold Spart's 4 chunk-planes into S (one row per block)
__global__ __launch_bounds__(64) void som_argmin(
    const float* __restrict__ dist,
    const float* __restrict__ Spart,
    float* __restrict__ out,
    float* __restrict__ S)
{
    const int b = blockIdx.x;
    const int lane = threadIdx.x;
    unsigned long long best = ~0ull;
    #pragma unroll
    for (int k = 0; k < 8; ++k) {
        const int jj = k * 64 + lane;
        const float s = dist[(size_t)b * O_DIM + jj];
        const unsigned long long key =
            ((unsigned long long)__float_as_uint(s) << 32) | (unsigned int)jj;
        best = key < best ? key : best;
    }
    #pragma unroll
    for (int m = 32; m >= 1; m >>= 1) {
        const unsigned long long o = __shfl_xor(best, m, 64);
        best = o < best ? o : best;
    }
    if (lane == 0) out[b] = (float)(unsigned int)(best & 0xFFFFFFFFull);

    const size_t SPLANE = (size_t)O_DIM * D_DIM;
    const size_t off = (size_t)b * D_DIM + lane * 2;   // row j = b of S
    const float2 s0 = *(const float2*)(Spart + off);
    const float2 s1 = *(const float2*)(Spart + SPLANE + off);
    const float2 s2 = *(const float2*)(Spart + 2 * SPLANE + off);
    const float2 s3 = *(const float2*)(Spart + 3 * SPLANE + off);
    float2 r;
    r.x = s0.x + s1.x + s2.x + s3.x;
    r.y = s0.y + s1.y + s2.y + s3.y;
    *(float2*)(S + off) = r;
}

// Pass 2: block = (j-tile of 8, i-chunk of 16). Per-thread S float4 loaded
// ONCE into a register and reused for 16 i-rows (S is loop-invariant in i).
// Pure 1-load+1-store stream; nontemporal so the output write doesn't evict
// the L3-resident W.
__global__ __launch_bounds__(256) void som_pass2(
    const float* __restrict__ W,
    const float* __restrict__ S,
    float* __restrict__ outW)
{
    const int jt = blockIdx.x >> 5;   // 0..63  -> j rows [jt*8, jt*8+8)
    const int ic = blockIdx.x & 31;   // 0..31  -> i rows [ic*16, ic*16+16)
    const int t  = threadIdx.x;

    const f32x4 s4 = *(const f32x4*)(S + (size_t)jt * 8 * D_DIM + t * 4);
    const size_t base = (size_t)(ic * 16) * O_DIM * D_DIM
                      + (size_t)jt * 8 * D_DIM + (size_t)t * 4;

    #pragma unroll 4
    for (int i = 0; i < 16; ++i) {
        const size_t e = base + (size_t)i * O_DIM * D_DIM;
        const f32x4 w4 = __builtin_nontemporal_load((const f32x4*)(W + e));
        const f32x4 o4 = w4 + s4;
        __builtin_nontemporal_store(o4, (f32x4*)(outW + e));
    }
}

// ---------------- fallback path (atomics, small ws) ----------------

__global__ __launch_bounds__(256) void som_pass1_atomic(
    const float* __restrict__ X, const float* __restrict__ W,
    float* __restrict__ S, unsigned long long* __restrict__ wkey)
{
    const int j = blockIdx.x >> 2, chunk = blockIdx.x & 3;
    const int wave = threadIdx.x >> 6, lane = threadIdx.x & 63;
    const int d0 = lane * 2;
    float accx = 0.f, accy = 0.f;
    const int b_end = chunk * 128 + 128;
    for (int b = chunk * 128 + wave; b < b_end; b += 4) {
        const float2 w2 = *(const float2*)(W + ((size_t)b * O_DIM + j) * D_DIM + d0);
        const float2 x2 = *(const float2*)(X + (size_t)b * D_DIM + d0);
        const float dx = w2.x - x2.x, dy = w2.y - x2.y;
        float s = dx * dx + dy * dy;
        #pragma unroll
        for (int m = 32; m >= 1; m >>= 1) s += __shfl_xor(s, m, 64);
        if (lane == 0)
            atomicMin(&wkey[b], ((unsigned long long)__float_as_uint(s) << 32) | (unsigned)j);
        const float c = LR * __expf(-s * INV2SIG2);
        accx -= c * dx; accy -= c * dy;
    }
    __shared__ float sacc[D_DIM];
    if (threadIdx.x < D_DIM) sacc[threadIdx.x] = 0.f;
    __syncthreads();
    atomicAdd(&sacc[d0], accx); atomicAdd(&sacc[d0 + 1], accy);
    __syncthreads();
    if (threadIdx.x < D_DIM) atomicAdd(&S[(size_t)j * D_DIM + threadIdx.x], sacc[threadIdx.x]);
}

__global__ __launch_bounds__(256) void som_pass2_atomic(
    const float* __restrict__ W, const float* __restrict__ S,
    const unsigned long long* __restrict__ wkey, float* __restrict__ out)
{
    const size_t tid = (size_t)blockIdx.x * blockDim.x + threadIdx.x;
    if (tid < O_DIM) out[tid] = (float)(unsigned int)(wkey[tid] & 0xFFFFFFFFull);
    float* __restrict__ outW = out + O_DIM;
    const size_t total4 = (size_t)O_DIM * O_DIM * D_DIM / 4;
    const size_t stride = (size_t)gridDim.x * blockDim.x;
    for (size_t i = tid; i < total4; i += stride) {
        const size_t e = i * 4;
        const float4 w4 = *(const float4*)(W + e);
        const float4 s4 = *(const float4*)(S + (e & (size_t)(O_DIM * D_DIM - 1)));
        float4 o4 = {w4.x + s4.x, w4.y + s4.y, w4.z + s4.z, w4.w + s4.w};
        *(float4*)(outW + e) = o4;
    }
}

extern "C" void kernel_launch(void* const* d_in, const int* in_sizes, int n_in,
                              void* d_out, int out_size, void* d_ws, size_t ws_size,
                              hipStream_t stream)
{
    const float* X = (const float*)d_in[0];   // (512, 128)
    const float* W = (const float*)d_in[1];   // (512, 512, 128)
    float* out = (float*)d_out;               // 512 winners + 512*512*128 weights

    const size_t DIST_BYTES  = (size_t)O_DIM * O_DIM * sizeof(float);   // 1 MiB
    const size_t SPART_BYTES = 4ull * O_DIM * D_DIM * sizeof(float);    // 1 MiB
    const size_t S_BYTES     = (size_t)O_DIM * D_DIM * sizeof(float);   // 256 KiB

    if (ws_size >= DIST_BYTES + SPART_BYTES + S_BYTES) {
        float* dist  = (float*)d_ws;
        float* Spart = (float*)((char*)d_ws + DIST_BYTES);
        float* S     = (float*)((char*)d_ws + DIST_BYTES + SPART_BYTES);
        som_pass1 <<<dim3(2048), dim3(256), 0, stream>>>(X, W, dist, Spart);
        som_argmin<<<dim3(512),  dim3(64),  0, stream>>>(dist, Spart, out, S);
        som_pass2 <<<dim3(2048), dim3(256), 0, stream>>>(W, S, out + O_DIM);
    } else {
        float* S = (float*)d_ws;
        unsigned long long* wkey =
            (unsigned long long*)((char*)d_ws + (size_t)O_DIM * D_DIM * sizeof(float));
        hipMemsetAsync(S, 0, (size_t)O_DIM * D_DIM * sizeof(float), stream);
        hipMemsetAsync(wkey, 0xFF, (size_t)O_DIM * sizeof(unsigned long long), stream);
        som_pass1_atomic<<<dim3(2048), dim3(256), 0, stream>>>(X, W, S, wkey);
        som_pass2_atomic<<<dim3(2048), dim3(256), 0, stream>>>(W, S, wkey, out);
    }
}

// Round 3
// 66.520 us; speedup vs baseline: 1.2709x; 1.1554x over previous
//
#include <hip/hip_runtime.h>
#include <stdint.h>

#define O_DIM 512
#define D_DIM 128
#define LR 0.01f
// 1 / (2 * sigma^2), sigma = 256 -> 1/131072
#define INV2SIG2 7.62939453125e-6f

typedef float f32x4 __attribute__((ext_vector_type(4)));

// ---------------- fast path ----------------
// ws layout:
//   [0, 1 MiB)          : dist[512][512]      float
//   [1 MiB, 2 MiB)      : Spart[4][512][128]  float

// Pass 1: block = (j, b-chunk of 128). 4 waves; each wave handles 4 b's at a
// time with 16 lanes per b (8 d-elements per lane). Reads each W element
// exactly once (134 MB HBM, W left L3-resident for pass2).
__global__ __launch_bounds__(256) void som_pass1(
    const float* __restrict__ X,
    const float* __restrict__ W,
    float* __restrict__ dist,
    float* __restrict__ Spart)
{
    const int j     = blockIdx.x >> 2;   // 0..511
    const int chunk = blockIdx.x & 3;    // 0..3
    const int wave  = threadIdx.x >> 6;  // 0..3
    const int lane  = threadIdx.x & 63;
    const int g     = lane >> 4;         // b-subgroup 0..3
    const int i16   = lane & 15;         // d-range within row
    const int dA    = i16 * 4;           // floats [dA, dA+4)
    const int dB    = 64 + dA;           // floats [dB, dB+4)

    float acc[8];
    #pragma unroll
    for (int u = 0; u < 8; ++u) acc[u] = 0.f;

    const int bbase = chunk * 128 + wave * 32 + g;   // + k*4, k=0..7

    #pragma unroll 2
    for (int k = 0; k < 8; ++k) {
        const int b = bbase + k * 4;
        const float* wrow = W + ((size_t)b * O_DIM + j) * D_DIM;
        const float* xrow = X + (size_t)b * D_DIM;
        const float4 wa = *(const float4*)(wrow + dA);
        const float4 wb = *(const float4*)(wrow + dB);
        const float4 xa = *(const float4*)(xrow + dA);
        const float4 xb = *(const float4*)(xrow + dB);

        float dx[8];
        dx[0] = wa.x - xa.x; dx[1] = wa.y - xa.y;
        dx[2] = wa.z - xa.z; dx[3] = wa.w - xa.w;
        dx[4] = wb.x - xb.x; dx[5] = wb.y - xb.y;
        dx[6] = wb.z - xb.z; dx[7] = wb.w - xb.w;

        float s = 0.f;
        #pragma unroll
        for (int u = 0; u < 8; ++u) s = fmaf(dx[u], dx[u], s);
        // reduce across the 16 lanes of this b
        s += __shfl_xor(s, 1, 64);
        s += __shfl_xor(s, 2, 64);
        s += __shfl_xor(s, 4, 64);
        s += __shfl_xor(s, 8, 64);

        if (i16 == 0) dist[(size_t)b * O_DIM + j] = s;

        const float c = LR * __expf(-s * INV2SIG2);
        #pragma unroll
        for (int u = 0; u < 8; ++u) acc[u] = fmaf(-c, dx[u], acc[u]); // c*(x-w)
    }

    // sum the 4 b-subgroups (lanes i16, i16+16, i16+32, i16+48)
    #pragma unroll
    for (int u = 0; u < 8; ++u) {
        acc[u] += __shfl_xor(acc[u], 16, 64);
        acc[u] += __shfl_xor(acc[u], 32, 64);
    }

    __shared__ float sacc[4][D_DIM];
    if (g == 0) {
        #pragma unroll
        for (int u = 0; u < 4; ++u) {
            sacc[wave][dA + u] = acc[u];
            sacc[wave][dB + u] = acc[4 + u];
        }
    }
    __syncthreads();
    if (threadIdx.x < D_DIM) {
        const int d = threadIdx.x;
        Spart[((size_t)chunk * O_DIM + j) * D_DIM + d] =
            sacc[0][d] + sacc[1][d] + sacc[2][d] + sacc[3][d];
    }
}

// Pass 2 (merged): per-block Spart->S fold (L2-resident, 4x16B per thread),
// argmin for row b=blockIdx.x in blocks 0..511 (one wave), then the
// W + S broadcast stream: plain (cached) W load — W is L3-hot from pass1 —
// and nontemporal store so the 134 MB output write doesn't evict W.
__global__ __launch_bounds__(256) void som_pass2(
    const float* __restrict__ W,
    const float* __restrict__ dist,
    const float* __restrict__ Spart,
    float* __restrict__ out)
{
    const int jt = blockIdx.x >> 5;   // 0..63  -> j rows [jt*8, jt*8+8)
    const int ic = blockIdx.x & 31;   // 0..31  -> i rows [ic*16, ic*16+16)
    const int t  = threadIdx.x;
    float* __restrict__ outW = out + O_DIM;

    // ---- argmin for row b = blockIdx.x (first wave of blocks 0..511) ----
    if (blockIdx.x < O_DIM && t < 64) {
        const int b = blockIdx.x;
        unsigned long long best = ~0ull;
        #pragma unroll
        for (int k = 0; k < 8; ++k) {
            const int jj = k * 64 + t;
            const float s = dist[(size_t)b * O_DIM + jj];
            const unsigned long long key =
                ((unsigned long long)__float_as_uint(s) << 32) | (unsigned int)jj;
            best = key < best ? key : best;
        }
        #pragma unroll
        for (int m = 32; m >= 1; m >>= 1) {
            const unsigned long long o = __shfl_xor(best, m, 64);
            best = o < best ? o : best;
        }
        if (t == 0) out[b] = (float)(unsigned int)(best & 0xFFFFFFFFull);
    }

    // ---- fold Spart's 4 chunk-planes into this thread's S float4 ----
    const size_t SPLANE = (size_t)O_DIM * D_DIM;
    const size_t soff = (size_t)jt * 8 * D_DIM + (size_t)t * 4;
    const f32x4 s0 = *(const f32x4*)(Spart + soff);
    const f32x4 s1 = *(const f32x4*)(Spart + SPLANE + soff);
    const f32x4 s2 = *(const f32x4*)(Spart + 2 * SPLANE + soff);
    const f32x4 s3 = *(const f32x4*)(Spart + 3 * SPLANE + soff);
    const f32x4 s4 = s0 + s1 + s2 + s3;

    // ---- stream: out[i][jt*8..+8][:] = W + S, S register-resident over 16 i ----
    const size_t base = (size_t)(ic * 16) * O_DIM * D_DIM + soff;
    #pragma unroll 4
    for (int i = 0; i < 16; ++i) {
        const size_t e = base + (size_t)i * O_DIM * D_DIM;
        const f32x4 w4 = *(const f32x4*)(W + e);
        __builtin_nontemporal_store(w4 + s4, (f32x4*)(outW + e));
    }
}

// ---------------- fallback path (atomics, small ws) ----------------

__global__ __launch_bounds__(256) void som_pass1_atomic(
    const float* __restrict__ X, const float* __restrict__ W,
    float* __restrict__ S, unsigned long long* __restrict__ wkey)
{
    const int j = blockIdx.x >> 2, chunk = blockIdx.x & 3;
    const int wave = threadIdx.x >> 6, lane = threadIdx.x & 63;
    const int d0 = lane * 2;
    float accx = 0.f, accy = 0.f;
    const int b_end = chunk * 128 + 128;
    for (int b = chunk * 128 + wave; b < b_end; b += 4) {
        const float2 w2 = *(const float2*)(W + ((size_t)b * O_DIM + j) * D_DIM + d0);
        const float2 x2 = *(const float2*)(X + (size_t)b * D_DIM + d0);
        const float dx = w2.x - x2.x, dy = w2.y - x2.y;
        float s = dx * dx + dy * dy;
        #pragma unroll
        for (int m = 32; m >= 1; m >>= 1) s += __shfl_xor(s, m, 64);
        if (lane == 0)
            atomicMin(&wkey[b], ((unsigned long long)__float_as_uint(s) << 32) | (unsigned)j);
        const float c = LR * __expf(-s * INV2SIG2);
        accx -= c * dx; accy -= c * dy;
    }
    __shared__ float sacc[D_DIM];
    if (threadIdx.x < D_DIM) sacc[threadIdx.x] = 0.f;
    __syncthreads();
    atomicAdd(&sacc[d0], accx); atomicAdd(&sacc[d0 + 1], accy);
    __syncthreads();
    if (threadIdx.x < D_DIM) atomicAdd(&S[(size_t)j * D_DIM + threadIdx.x], sacc[threadIdx.x]);
}

__global__ __launch_bounds__(256) void som_pass2_atomic(
    const float* __restrict__ W, const float* __restrict__ S,
    const unsigned long long* __restrict__ wkey, float* __restrict__ out)
{
    const size_t tid = (size_t)blockIdx.x * blockDim.x + threadIdx.x;
    if (tid < O_DIM) out[tid] = (float)(unsigned int)(wkey[tid] & 0xFFFFFFFFull);
    float* __restrict__ outW = out + O_DIM;
    const size_t total4 = (size_t)O_DIM * O_DIM * D_DIM / 4;
    const size_t stride = (size_t)gridDim.x * blockDim.x;
    for (size_t i = tid; i < total4; i += stride) {
        const size_t e = i * 4;
        const float4 w4 = *(const float4*)(W + e);
        const float4 s4 = *(const float4*)(S + (e & (size_t)(O_DIM * D_DIM - 1)));
        float4 o4 = {w4.x + s4.x, w4.y + s4.y, w4.z + s4.z, w4.w + s4.w};
        *(float4*)(outW + e) = o4;
    }
}

extern "C" void kernel_launch(void* const* d_in, const int* in_sizes, int n_in,
                              void* d_out, int out_size, void* d_ws, size_t ws_size,
                              hipStream_t stream)
{
    const float* X = (const float*)d_in[0];   // (512, 128)
    const float* W = (const float*)d_in[1];   // (512, 512, 128)
    float* out = (float*)d_out;               // 512 winners + 512*512*128 weights

    const size_t DIST_BYTES  = (size_t)O_DIM * O_DIM * sizeof(float);   // 1 MiB
    const size_t SPART_BYTES = 4ull * O_DIM * D_DIM * sizeof(float);    // 1 MiB

    if (ws_size >= DIST_BYTES + SPART_BYTES) {
        float* dist  = (float*)d_ws;
        float* Spart = (float*)((char*)d_ws + DIST_BYTES);
        som_pass1<<<dim3(2048), dim3(256), 0, stream>>>(X, W, dist, Spart);
        som_pass2<<<dim3(2048), dim3(256), 0, stream>>>(W, dist, Spart, out);
    } else {
        float* S = (float*)d_ws;
        unsigned long long* wkey =
            (unsigned long long*)((char*)d_ws + (size_t)O_DIM * D_DIM * sizeof(float));
        hipMemsetAsync(S, 0, (size_t)O_DIM * D_DIM * sizeof(float), stream);
        hipMemsetAsync(wkey, 0xFF, (size_t)O_DIM * sizeof(unsigned long long), stream);
        som_pass1_atomic<<<dim3(2048), dim3(256), 0, stream>>>(X, W, S, wkey);
        som_pass2_atomic<<<dim3(2048), dim3(256), 0, stream>>>(W, S, wkey, out);
    }
}

// Round 4
// 65.578 us; speedup vs baseline: 1.2892x; 1.0144x over previous
//
#include <hip/hip_runtime.h>
#include <stdint.h>

#define O_DIM 512
#define D_DIM 128
#define LR 0.01f
// 1 / (2 * sigma^2), sigma = 256 -> 1/131072
#define INV2SIG2 7.62939453125e-6f

typedef float f32x4 __attribute__((ext_vector_type(4)));

// ---------------- fast path ----------------
// ws layout: [0, 1 MiB) : dist[512][512] float
//
// Fused column-owner kernel: block j owns W[:, j, :] (256 KB).
//   Phase A: read column, compute dist[:, j] and the COMPLETE S[j] (the
//            weight-update row depends only on column j -> block-local).
//   Phase B: immediately re-read the column (short re-read distance ->
//            L2/L3-hot) and stream out[:, j, :] = W[:, j, :] + S[j],
//            nontemporal store.
// Winner argmin (row-wise over dist) is the only cross-block dependency ->
// tiny second kernel.
__global__ __launch_bounds__(256) void som_fused(
    const float* __restrict__ X,
    const float* __restrict__ W,
    float* __restrict__ dist,
    float* __restrict__ outW)
{
    const int j    = blockIdx.x;         // 0..511
    const int wave = threadIdx.x >> 6;   // 0..3
    const int lane = threadIdx.x & 63;
    const int g    = lane >> 4;          // b-subgroup 0..3
    const int i16  = lane & 15;          // d-slice within row
    const int dA   = i16 * 4;            // floats [dA, dA+4)
    const int dB   = 64 + dA;            // floats [dB, dB+4)

    float acc[8];
    #pragma unroll
    for (int u = 0; u < 8; ++u) acc[u] = 0.f;

    const int bbase = wave * 4 + g;      // + k*16, k = 0..31

    // ---------------- phase A ----------------
    #pragma unroll 2
    for (int k = 0; k < 32; k += 4) {
        float4 wa[4], wb[4], xa[4], xb[4];
        int bb[4];
        #pragma unroll
        for (int u = 0; u < 4; ++u) {
            bb[u] = bbase + (k + u) * 16;
            const float* wrow = W + ((size_t)bb[u] * O_DIM + j) * D_DIM;
            const float* xrow = X + (size_t)bb[u] * D_DIM;
            wa[u] = *(const float4*)(wrow + dA);
            wb[u] = *(const float4*)(wrow + dB);
            xa[u] = *(const float4*)(xrow + dA);
            xb[u] = *(const float4*)(xrow + dB);
        }
        #pragma unroll
        for (int u = 0; u < 4; ++u) {
            float dx[8];
            dx[0] = wa[u].x - xa[u].x; dx[1] = wa[u].y - xa[u].y;
            dx[2] = wa[u].z - xa[u].z; dx[3] = wa[u].w - xa[u].w;
            dx[4] = wb[u].x - xb[u].x; dx[5] = wb[u].y - xb[u].y;
            dx[6] = wb[u].z - xb[u].z; dx[7] = wb[u].w - xb[u].w;

            float s = 0.f;
            #pragma unroll
            for (int v = 0; v < 8; ++v) s = fmaf(dx[v], dx[v], s);
            // reduce across the 16 lanes of this b
            s += __shfl_xor(s, 1, 64);
            s += __shfl_xor(s, 2, 64);
            s += __shfl_xor(s, 4, 64);
            s += __shfl_xor(s, 8, 64);

            if (i16 == 0) dist[(size_t)bb[u] * O_DIM + j] = s;

            const float c = LR * __expf(-s * INV2SIG2);
            #pragma unroll
            for (int v = 0; v < 8; ++v) acc[v] = fmaf(-c, dx[v], acc[v]); // c*(x-w)
        }
    }

    // ---- reduce acc across b-subgroups (lanes i16, +16, +32, +48) ----
    #pragma unroll
    for (int u = 0; u < 8; ++u) {
        acc[u] += __shfl_xor(acc[u], 16, 64);
        acc[u] += __shfl_xor(acc[u], 32, 64);
    }

    __shared__ float sacc[4][D_DIM];
    __shared__ float sS[D_DIM];
    if (g == 0) {
        #pragma unroll
        for (int u = 0; u < 4; ++u) {
            sacc[wave][dA + u] = acc[u];
            sacc[wave][dB + u] = acc[4 + u];
        }
    }
    __syncthreads();
    if (threadIdx.x < D_DIM) {
        const int d = threadIdx.x;
        sS[d] = sacc[0][d] + sacc[1][d] + sacc[2][d] + sacc[3][d];
    }
    __syncthreads();

    const f32x4 sA = *(const f32x4*)(sS + dA);
    const f32x4 sB = *(const f32x4*)(sS + dB);

    // ---------------- phase B: out[:, j, :] = W[:, j, :] + S[j] ----------------
    #pragma unroll 4
    for (int k = 0; k < 32; ++k) {
        const int b = bbase + k * 16;
        const size_t e = ((size_t)b * O_DIM + j) * D_DIM;
        const f32x4 w4a = *(const f32x4*)(W + e + dA);
        const f32x4 w4b = *(const f32x4*)(W + e + dB);
        __builtin_nontemporal_store(w4a + sA, (f32x4*)(outW + e + dA));
        __builtin_nontemporal_store(w4b + sB, (f32x4*)(outW + e + dB));
    }
}

// row-wise argmin over j for each b
__global__ __launch_bounds__(64) void som_argmin(
    const float* __restrict__ dist,
    float* __restrict__ out)
{
    const int b = blockIdx.x;
    const int lane = threadIdx.x;
    unsigned long long best = ~0ull;
    #pragma unroll
    for (int k = 0; k < 8; ++k) {
        const int jj = k * 64 + lane;
        const float s = dist[(size_t)b * O_DIM + jj];
        const unsigned long long key =
            ((unsigned long long)__float_as_uint(s) << 32) | (unsigned int)jj;
        best = key < best ? key : best;
    }
    #pragma unroll
    for (int m = 32; m >= 1; m >>= 1) {
        const unsigned long long o = __shfl_xor(best, m, 64);
        best = o < best ? o : best;
    }
    if (lane == 0) out[b] = (float)(unsigned int)(best & 0xFFFFFFFFull);
}

// ---------------- fallback path (atomics, small ws) ----------------

__global__ __launch_bounds__(256) void som_pass1_atomic(
    const float* __restrict__ X, const float* __restrict__ W,
    float* __restrict__ S, unsigned long long* __restrict__ wkey)
{
    const int j = blockIdx.x >> 2, chunk = blockIdx.x & 3;
    const int wave = threadIdx.x >> 6, lane = threadIdx.x & 63;
    const int d0 = lane * 2;
    float accx = 0.f, accy = 0.f;
    const int b_end = chunk * 128 + 128;
    for (int b = chunk * 128 + wave; b < b_end; b += 4) {
        const float2 w2 = *(const float2*)(W + ((size_t)b * O_DIM + j) * D_DIM + d0);
        const float2 x2 = *(const float2*)(X + (size_t)b * D_DIM + d0);
        const float dx = w2.x - x2.x, dy = w2.y - x2.y;
        float s = dx * dx + dy * dy;
        #pragma unroll
        for (int m = 32; m >= 1; m >>= 1) s += __shfl_xor(s, m, 64);
        if (lane == 0)
            atomicMin(&wkey[b], ((unsigned long long)__float_as_uint(s) << 32) | (unsigned)j);
        const float c = LR * __expf(-s * INV2SIG2);
        accx -= c * dx; accy -= c * dy;
    }
    __shared__ float sacc[D_DIM];
    if (threadIdx.x < D_DIM) sacc[threadIdx.x] = 0.f;
    __syncthreads();
    atomicAdd(&sacc[d0], accx); atomicAdd(&sacc[d0 + 1], accy);
    __syncthreads();
    if (threadIdx.x < D_DIM) atomicAdd(&S[(size_t)j * D_DIM + threadIdx.x], sacc[threadIdx.x]);
}

__global__ __launch_bounds__(256) void som_pass2_atomic(
    const float* __restrict__ W, const float* __restrict__ S,
    const unsigned long long* __restrict__ wkey, float* __restrict__ out)
{
    const size_t tid = (size_t)blockIdx.x * blockDim.x + threadIdx.x;
    if (tid < O_DIM) out[tid] = (float)(unsigned int)(wkey[tid] & 0xFFFFFFFFull);
    float* __restrict__ outW = out + O_DIM;
    const size_t total4 = (size_t)O_DIM * O_DIM * D_DIM / 4;
    const size_t stride = (size_t)gridDim.x * blockDim.x;
    for (size_t i = tid; i < total4; i += stride) {
        const size_t e = i * 4;
        const float4 w4 = *(const float4*)(W + e);
        const float4 s4 = *(const float4*)(S + (e & (size_t)(O_DIM * D_DIM - 1)));
        float4 o4 = {w4.x + s4.x, w4.y + s4.y, w4.z + s4.z, w4.w + s4.w};
        *(float4*)(outW + e) = o4;
    }
}

extern "C" void kernel_launch(void* const* d_in, const int* in_sizes, int n_in,
                              void* d_out, int out_size, void* d_ws, size_t ws_size,
                              hipStream_t stream)
{
    const float* X = (const float*)d_in[0];   // (512, 128)
    const float* W = (const float*)d_in[1];   // (512, 512, 128)
    float* out = (float*)d_out;               // 512 winners + 512*512*128 weights

    const size_t DIST_BYTES = (size_t)O_DIM * O_DIM * sizeof(float);   // 1 MiB

    if (ws_size >= DIST_BYTES) {
        float* dist = (float*)d_ws;
        som_fused <<<dim3(512), dim3(256), 0, stream>>>(X, W, dist, out + O_DIM);
        som_argmin<<<dim3(512), dim3(64),  0, stream>>>(dist, out);
    } else {
        float* S = (float*)d_ws;
        unsigned long long* wkey =
            (unsigned long long*)((char*)d_ws + (size_t)O_DIM * D_DIM * sizeof(float));
        hipMemsetAsync(S, 0, (size_t)O_DIM * D_DIM * sizeof(float), stream);
        hipMemsetAsync(wkey, 0xFF, (size_t)O_DIM * sizeof(unsigned long long), stream);
        som_pass1_atomic<<<dim3(2048), dim3(256), 0, stream>>>(X, W, S, wkey);
        som_pass2_atomic<<<dim3(2048), dim3(256), 0, stream>>>(W, S, wkey, out);
    }
}